// Round 15
// baseline (593.691 us; speedup 1.0000x reference)
//
#include <hip/hip_runtime.h>
#include <hip/hip_fp16.h>
#include <math.h>

#define N_B 16
#define N_A 1024
#define N_D 1024
#define N_H 512
#define N_W 512

typedef _Float16 half2t __attribute__((ext_vector_type(2)));

__device__ inline half2t h2cast(unsigned u) {
    union { unsigned u; half2t h; } cv; cv.u = u; return cv.h;
}

__device__ inline float fdot2f(half2t a, half2t b, float c) {
#if __has_builtin(__builtin_amdgcn_fdot2)
    return __builtin_amdgcn_fdot2(a, b, c, false);
#else
    asm("v_dot2_f32_f16 %0, %1, %2, %0" : "+v"(c) : "v"(a), "v"(b));
    return c;
#endif
}

__device__ inline half2t pack_h2(float lo, float hi) {
#if __has_builtin(__builtin_amdgcn_cvt_pkrtz)
    auto r = __builtin_amdgcn_cvt_pkrtz(lo, hi);
    union { decltype(r) a; half2t h; } cv; cv.a = r; return cv.h;
#else
    half2t r; r.x = (_Float16)lo; r.y = (_Float16)hi; return r;
#endif
}

__device__ inline unsigned pack_u(float lo, float hi) {
    union { half2t h; unsigned u; } cv; cv.h = pack_h2(lo, hi); return cv.u;
}

__device__ inline float med3f(float a, float lo, float hi) {
#if __has_builtin(__builtin_amdgcn_fmed3f)
    return __builtin_amdgcn_fmed3f(a, lo, hi);
#else
    return fminf(fmaxf(a, lo), hi);
#endif
}

// ---------------------------------------------------------------------------
__global__ void fan_setup_kernel(const float* __restrict__ angles,
                                 float* __restrict__ twr,
                                 float* __restrict__ twi,
                                 float2* __restrict__ cs) {
    int t = blockIdx.x * 256 + threadIdx.x;
    if (t < 512) {
        double ang = -2.0 * M_PI * (double)t / 1024.0;
        twr[t] = (float)cos(ang);
        twi[t] = (float)sin(ang);
    }
    if (t < 1024) {
        double b = (double)angles[t];
        cs[t] = make_float2((float)cos(b), (float)sin(b));
    }
}

// ---------------------------------------------------------------------------
// Per (32x32-tile, angle) window base: u monotone along tile rows/columns
// (see r14 proof), so tile min = corner min; |grad idx| <= 3.38 bins/px ->
// span <= ~148 << 256. base = floor(min)-2, clamped to [0, 768].
// ---------------------------------------------------------------------------
__global__ __launch_bounds__(256) void fan_umin_kernel(
    const float2* __restrict__ cs, unsigned* __restrict__ utab) {
    const int t = blockIdx.x * 256 + threadIdx.x;  // 256 tiles * 1024 angles
    const int a = t & (N_A - 1);
    const int tile = t >> 10;
    const float2 p = cs[a];
    const float c = p.x, s = p.y;
    const float x0 = (float)((tile & 15) * 32) - 255.5f;
    const float x1 = x0 + 31.0f;
    const float y0 = (float)((tile >> 4) * 32) - 255.5f;
    const float y1 = y0 + 31.0f;
    float m = 1e30f;
#pragma unroll
    for (int i = 0; i < 4; ++i) {
        const float xx = (i & 1) ? x1 : x0;
        const float yy = (i & 2) ? y1 : y0;
        const float tt = 750.0f + xx * c + yy * s;
        const float idx = (960.0f * (yy * c - xx * s)) / tt + 511.5f;
        m = fminf(m, idx);
    }
    int base = (int)floorf(m) - 2;
    base = base < 0 ? 0 : (base > 768 ? 768 : base);
    utab[t] = (unsigned)base;
}

// ---------------------------------------------------------------------------
// FFT ramp filter: output [g][a][d], 16B entries = 4 batches' bilinear half2
// pair (f[d], f[d+1]).
// ---------------------------------------------------------------------------
__global__ __launch_bounds__(256) void fan_fft_filter4_kernel(
    const float* __restrict__ sino, const float* __restrict__ filt,
    const float* __restrict__ twr_g, const float* __restrict__ twi_g,
    uint4* __restrict__ pf4) {
    __shared__ float s_re0[1024], s_im0[1024];
    __shared__ float s_re1[1024], s_im1[1024];
    __shared__ float s_twr[512], s_twi[512];

    const int tid = threadIdx.x;
    const int a = blockIdx.x & (N_A - 1);
    const int g = blockIdx.x >> 10;

    {
        float2 t0 = ((const float2*)twr_g)[tid];
        s_twr[2 * tid] = t0.x; s_twr[2 * tid + 1] = t0.y;
        float2 t1 = ((const float2*)twi_g)[tid];
        s_twi[2 * tid] = t1.x; s_twi[2 * tid + 1] = t1.y;
    }
    {
        const size_t rowstride = (size_t)N_A * N_D;
        const float* rb = sino + (size_t)(4 * g) * rowstride + (size_t)a * N_D;
        ((float4*)s_re0)[tid] = ((const float4*)(rb + 0 * rowstride))[tid];
        ((float4*)s_im0)[tid] = ((const float4*)(rb + 1 * rowstride))[tid];
        ((float4*)s_re1)[tid] = ((const float4*)(rb + 2 * rowstride))[tid];
        ((float4*)s_im1)[tid] = ((const float4*)(rb + 3 * rowstride))[tid];
    }
    __syncthreads();

    for (int L = 9; L >= 0; --L) {
        const int half = 1 << L;
#pragma unroll
        for (int q = 0; q < 4; ++q) {
            float* re = (q < 2) ? s_re0 : s_re1;
            float* im = (q < 2) ? s_im0 : s_im1;
            const int bf = tid + ((q & 1) << 8);
            const int j = bf & (half - 1);
            const int blk = bf >> L;
            const int base = (blk << (L + 1)) + j;
            const int tw = j << (9 - L);
            const float wr = s_twr[tw], wi = s_twi[tw];
            const float ar = re[base], ai = im[base];
            const float br = re[base + half], bi = im[base + half];
            re[base] = ar + br;
            im[base] = ai + bi;
            const float dr = ar - br, di = ai - bi;
            re[base + half] = dr * wr - di * wi;
            im[base + half] = dr * wi + di * wr;
        }
        __syncthreads();
    }

#pragma unroll
    for (int q = 0; q < 4; ++q) {
        const int i = tid + (q << 8);
        const int ri = (int)(__brev((unsigned)i) >> 22);
        const float f = filt[ri];
        s_re0[i] *= f; s_im0[i] *= f;
        s_re1[i] *= f; s_im1[i] *= f;
    }
    __syncthreads();

    for (int L = 0; L <= 9; ++L) {
        const int half = 1 << L;
#pragma unroll
        for (int q = 0; q < 4; ++q) {
            float* re = (q < 2) ? s_re0 : s_re1;
            float* im = (q < 2) ? s_im0 : s_im1;
            const int bf = tid + ((q & 1) << 8);
            const int j = bf & (half - 1);
            const int blk = bf >> L;
            const int base = (blk << (L + 1)) + j;
            const int tw = j << (9 - L);
            const float wr = s_twr[tw], wi = -s_twi[tw];
            const float ar = re[base], ai = im[base];
            const float tr = re[base + half], ti = im[base + half];
            const float br = tr * wr - ti * wi;
            const float bi = tr * wi + ti * wr;
            re[base] = ar + br;
            im[base] = ai + bi;
            re[base + half] = ar - br;
            im[base + half] = ai - bi;
        }
        __syncthreads();
    }

    const float invN = 1.0f / 1024.0f;
    uint4* dst = pf4 + ((size_t)g * N_A + (size_t)a) * N_D;
#pragma unroll
    for (int q = 0; q < 4; ++q) {
        const int n = tid + (q << 8);
        const int n1 = (n < 1023) ? n + 1 : n;
        const float e = (n < 1023) ? 1.0f : 0.0f;
        uint4 v;
        v.x = pack_u(s_re0[n] * invN, s_re0[n1] * invN * e);
        v.y = pack_u(s_im0[n] * invN, s_im0[n1] * invN * e);
        v.z = pack_u(s_re1[n] * invN, s_re1[n1] * invN * e);
        v.w = pack_u(s_im1[n] * invN, s_im1[n1] * invN * e);
        dst[n] = v;
    }
}

// ---------------------------------------------------------------------------
// Backprojection, hybrid pipes, 2 PIXELS PER THREAD: 512-thread block covers
// a 32x32 tile; thread owns (x, y) and (x, y+16). Groups 0,1 -> direct TCP
// gathers; groups 2,3 -> 256-entry double-buffered LDS window (uint4/lane
// staging). Geometry for pixel 1 by linear update (t1 = t0+16s,
// num1 = num0+16c). One __syncthreads per angle (sound with dbuf).
// ---------------------------------------------------------------------------
template <int SPLIT>
__global__ __launch_bounds__(512) void fan_backproject_kernel(
    const uint4* __restrict__ pf4, const float2* __restrict__ cs_g,
    const unsigned* __restrict__ utab, float* __restrict__ dst0) {
    constexpr int ACNT = N_A / SPLIT;
    __shared__ float2 lcs[ACNT];
    __shared__ unsigned s_ub[ACNT];
    __shared__ uint4 win[2][512];  // 16 KB: [buf][g*256 + e]
    const int tid = threadIdx.x;   // 0..511

    int part, tile;
    if (SPLIT == 4) {
        part = blockIdx.x & 3;   // round-robin: XCD-local angle slice
        tile = blockIdx.x >> 2;
    } else {
        part = 0;
        tile = blockIdx.x;
    }
    const int abase = part * ACNT;

    // stage loop tables
    const unsigned* __restrict__ utrow = utab + (size_t)tile * N_A + abase;
    for (int i = tid; i < ACNT; i += 512) {
        lcs[i] = cs_g[abase + i];
        s_ub[i] = utrow[i];
    }

    const int xi = (tile & 15) * 32 + (tid & 31);
    const int yi0 = (tile >> 4) * 32 + (tid >> 5);  // rows 0..15 of tile
    const float x = (float)xi - 255.5f;
    const float y0 = (float)yi0 - 255.5f;

    const uint4* __restrict__ g0 = pf4;                       // batches 0-3
    const uint4* __restrict__ g1 = pf4 + ((size_t)1 << 20);   // batches 4-7
    // staging: thread covers uint4 chunk tid of the 8KB window image:
    // sg = tid>>8 (0 -> group2, 1 -> group3), se = tid&255
    const unsigned sg = (unsigned)tid >> 8;
    const unsigned se = (unsigned)tid & 255u;
    const uint4* __restrict__ gsrc = pf4 + ((size_t)(2 + sg) << 20);

    float acc0[N_B], acc1[N_B];
#pragma unroll
    for (int b = 0; b < N_B; ++b) { acc0[b] = 0.0f; acc1[b] = 0.0f; }

    __syncthreads();  // tables ready

    // prefetch window(0)
    uint4 pre;
    {
        const unsigned e = s_ub[0] + se;  // <= 768+255 = 1023, in range
        pre = gsrc[(((unsigned)abase) << 10) + e];
    }

    for (int k = 0; k < ACNT; ++k) {
        win[k & 1][tid] = pre;
        if (k + 1 < ACNT) {
            const unsigned e = s_ub[k + 1] + se;
            pre = gsrc[(((unsigned)(abase + k + 1)) << 10) + e];
        }
        __syncthreads();  // buf[k&1] visible; fences dbuf reuse

        const float2 csp = lcs[k];
        const float c = csp.x, s = csp.y;
        const unsigned ub = s_ub[k];
        const unsigned abk = ((unsigned)(abase + k)) << 10;
        const uint4* wbuf = &win[k & 1][0];

        // pixel 0 geometry
        const float t0 = fmaf(x, c, fmaf(y0, s, 750.0f));
        const float num0 = fmaf(y0, c, -(x * s));
        // pixel 1 geometry by linear update (y1 = y0 + 16)
        const float t1 = fmaf(16.0f, s, t0);
        const float num1 = fmaf(16.0f, c, num0);

        const float r0 = __builtin_amdgcn_rcpf(t0);
        const float r1 = __builtin_amdgcn_rcpf(t1);
        const float idxA = fmaf(num0 * r0, 960.0f, 511.5f);
        const float idxB = fmaf(num1 * r1, 960.0f, 511.5f);
        const float idxcA = med3f(idxA, 0.0f, 1023.0f);
        const float idxcB = med3f(idxB, 0.0f, 1023.0f);
        const float i0fA = floorf(idxcA);
        const float i0fB = floorf(idxcB);
        const float frA = idxcA - i0fA;
        const float frB = idxcB - i0fB;
        const float waA = 750.0f * r0, waB = 750.0f * r1;
        float wdA = waA * waA, wdB = waB * waB;
        wdA = (idxA == idxcA) ? wdA : 0.0f;
        wdB = (idxB == idxcB) ? wdB : 0.0f;
        const float w1A = wdA * frA, w1B = wdB * frB;
        const half2t wpA = pack_h2(wdA - w1A, w1A);
        const half2t wpB = pack_h2(wdB - w1B, w1B);
        const int i0A = (int)i0fA, i0B = (int)i0fB;
        const unsigned offA = abk + (unsigned)i0A;
        const unsigned offB = abk + (unsigned)i0B;
        int oiA = i0A - (int)ub, oiB = i0B - (int)ub;
        oiA = oiA < 0 ? 0 : (oiA > 255 ? 255 : oiA);  // w=0 cases only
        oiB = oiB < 0 ? 0 : (oiB > 255 ? 255 : oiB);

        const uint4 a0 = g0[offA];
        const uint4 a1 = g1[offA];
        const uint4 a2 = wbuf[(unsigned)oiA];
        const uint4 a3 = wbuf[256u + (unsigned)oiA];
        const uint4 b0 = g0[offB];
        const uint4 b1 = g1[offB];
        const uint4 b2 = wbuf[(unsigned)oiB];
        const uint4 b3 = wbuf[256u + (unsigned)oiB];

        acc0[0] = fdot2f(h2cast(a0.x), wpA, acc0[0]);
        acc0[1] = fdot2f(h2cast(a0.y), wpA, acc0[1]);
        acc0[2] = fdot2f(h2cast(a0.z), wpA, acc0[2]);
        acc0[3] = fdot2f(h2cast(a0.w), wpA, acc0[3]);
        acc0[4] = fdot2f(h2cast(a1.x), wpA, acc0[4]);
        acc0[5] = fdot2f(h2cast(a1.y), wpA, acc0[5]);
        acc0[6] = fdot2f(h2cast(a1.z), wpA, acc0[6]);
        acc0[7] = fdot2f(h2cast(a1.w), wpA, acc0[7]);
        acc0[8] = fdot2f(h2cast(a2.x), wpA, acc0[8]);
        acc0[9] = fdot2f(h2cast(a2.y), wpA, acc0[9]);
        acc0[10] = fdot2f(h2cast(a2.z), wpA, acc0[10]);
        acc0[11] = fdot2f(h2cast(a2.w), wpA, acc0[11]);
        acc0[12] = fdot2f(h2cast(a3.x), wpA, acc0[12]);
        acc0[13] = fdot2f(h2cast(a3.y), wpA, acc0[13]);
        acc0[14] = fdot2f(h2cast(a3.z), wpA, acc0[14]);
        acc0[15] = fdot2f(h2cast(a3.w), wpA, acc0[15]);

        acc1[0] = fdot2f(h2cast(b0.x), wpB, acc1[0]);
        acc1[1] = fdot2f(h2cast(b0.y), wpB, acc1[1]);
        acc1[2] = fdot2f(h2cast(b0.z), wpB, acc1[2]);
        acc1[3] = fdot2f(h2cast(b0.w), wpB, acc1[3]);
        acc1[4] = fdot2f(h2cast(b1.x), wpB, acc1[4]);
        acc1[5] = fdot2f(h2cast(b1.y), wpB, acc1[5]);
        acc1[6] = fdot2f(h2cast(b1.z), wpB, acc1[6]);
        acc1[7] = fdot2f(h2cast(b1.w), wpB, acc1[7]);
        acc1[8] = fdot2f(h2cast(b2.x), wpB, acc1[8]);
        acc1[9] = fdot2f(h2cast(b2.y), wpB, acc1[9]);
        acc1[10] = fdot2f(h2cast(b2.z), wpB, acc1[10]);
        acc1[11] = fdot2f(h2cast(b2.w), wpB, acc1[11]);
        acc1[12] = fdot2f(h2cast(b3.x), wpB, acc1[12]);
        acc1[13] = fdot2f(h2cast(b3.y), wpB, acc1[13]);
        acc1[14] = fdot2f(h2cast(b3.z), wpB, acc1[14]);
        acc1[15] = fdot2f(h2cast(b3.w), wpB, acc1[15]);
    }

    const float scale = 3.14159265358979323846f / 1024.0f;  // pi / A
    float* dst = dst0 + (size_t)part * ((size_t)N_B * N_H * N_W);
    const size_t pix0 = (size_t)yi0 * N_W + (size_t)xi;
    const size_t pix1 = pix0 + (size_t)16 * N_W;
#pragma unroll
    for (int b = 0; b < N_B; ++b) {
        dst[(size_t)b * (N_H * N_W) + pix0] = acc0[b] * scale;
        dst[(size_t)b * (N_H * N_W) + pix1] = acc1[b] * scale;
    }
}

// ---------------------------------------------------------------------------
template <int NS>
__global__ __launch_bounds__(256) void fan_reduce_kernel(
    const float4* __restrict__ p, float4* __restrict__ o) {
    const int i = blockIdx.x * 256 + threadIdx.x;
    const size_t stride = (size_t)N_B * N_H * N_W / 4;
    float4 v = p[i];
#pragma unroll
    for (int k = 1; k < NS; ++k) {
        const float4 w = p[(size_t)k * stride + i];
        v.x += w.x; v.y += w.y; v.z += w.z; v.w += w.w;
    }
    o[i] = v;
}

// ---------------------------------------------------------------------------
extern "C" void kernel_launch(void* const* d_in, const int* in_sizes, int n_in,
                              void* d_out, int out_size, void* d_ws, size_t ws_size,
                              hipStream_t stream) {
    const float* sino = (const float*)d_in[0];    // [16, 1024, 1024] f32
    const float* filt = (const float*)d_in[1];    // [1024] f32
    const float* angles = (const float*)d_in[2];  // [1024] f32
    float* out = (float*)d_out;                   // [16, 512, 512] f32

    float* twr = (float*)d_ws;
    float* twi = twr + 512;
    float2* cs = (float2*)(twi + 512);
    char* base = (char*)d_ws;
    unsigned* utab = (unsigned*)(base + 16384);            // 1 MB
    uint4* pf4 = (uint4*)(base + 16384 + (1 << 20));
    const size_t PF_BYTES = (size_t)4 * N_A * N_D * 16;    // 64 MB
    float* partials = (float*)(base + 16384 + (1 << 20) + PF_BYTES);
    const size_t PART = (size_t)N_B * N_H * N_W;           // 4M floats
    const size_t need4 = 16384 + (1 << 20) + PF_BYTES + 4 * PART * 4;
    const size_t need1 = 16384 + (1 << 20) + PF_BYTES;

    fan_setup_kernel<<<4, 256, 0, stream>>>(angles, twr, twi, cs);
    fan_umin_kernel<<<1024, 256, 0, stream>>>(cs, utab);
    fan_fft_filter4_kernel<<<4 * N_A, 256, 0, stream>>>(sino, filt, twr, twi,
                                                        pf4);
    if (ws_size >= need4) {
        fan_backproject_kernel<4><<<256 * 4, 512, 0, stream>>>(pf4, cs, utab,
                                                               partials);
        fan_reduce_kernel<4><<<(int)(PART / 4 / 256), 256, 0, stream>>>(
            (const float4*)partials, (float4*)out);
    } else if (ws_size >= need1) {
        fan_backproject_kernel<1><<<256, 512, 0, stream>>>(pf4, cs, utab,
                                                           out);
    }
}

// Round 17
// 484.669 us; speedup vs baseline: 1.2249x; 1.2249x over previous
//
#include <hip/hip_runtime.h>
#include <hip/hip_fp16.h>
#include <math.h>

#define N_B 16
#define N_A 1024
#define N_D 1024
#define N_H 512
#define N_W 512

typedef _Float16 half2t __attribute__((ext_vector_type(2)));

__device__ inline half2t h2cast(unsigned u) {
    union { unsigned u; half2t h; } cv; cv.u = u; return cv.h;
}

__device__ inline float fdot2f(half2t a, half2t b, float c) {
#if __has_builtin(__builtin_amdgcn_fdot2)
    return __builtin_amdgcn_fdot2(a, b, c, false);
#else
    asm("v_dot2_f32_f16 %0, %1, %2, %0" : "+v"(c) : "v"(a), "v"(b));
    return c;
#endif
}

__device__ inline half2t pack_h2(float lo, float hi) {
#if __has_builtin(__builtin_amdgcn_cvt_pkrtz)
    auto r = __builtin_amdgcn_cvt_pkrtz(lo, hi);
    union { decltype(r) a; half2t h; } cv; cv.a = r; return cv.h;
#else
    half2t r; r.x = (_Float16)lo; r.y = (_Float16)hi; return r;
#endif
}

__device__ inline unsigned pack_u(float lo, float hi) {
    union { half2t h; unsigned u; } cv; cv.h = pack_h2(lo, hi); return cv.u;
}

__device__ inline float med3f(float a, float lo, float hi) {
#if __has_builtin(__builtin_amdgcn_fmed3f)
    return __builtin_amdgcn_fmed3f(a, lo, hi);
#else
    return fminf(fmaxf(a, lo), hi);
#endif
}

// ---------------------------------------------------------------------------
__global__ void fan_setup_kernel(const float* __restrict__ angles,
                                 float* __restrict__ twr,
                                 float* __restrict__ twi,
                                 float2* __restrict__ cs) {
    int t = blockIdx.x * 256 + threadIdx.x;
    if (t < 512) {
        double ang = -2.0 * M_PI * (double)t / 1024.0;
        twr[t] = (float)cos(ang);
        twi[t] = (float)sin(ang);
    }
    if (t < 1024) {
        double b = (double)angles[t];
        cs[t] = make_float2((float)cos(b), (float)sin(b));
    }
}

// ---------------------------------------------------------------------------
// Per (32x32-tile, angle) window base: u monotone along tile rows/columns
// (du/dx sign indep. of x, du/dy sign indep. of y), so tile min = corner
// min; |grad idx| <= 3.38 bins/px -> span <= ~148 << 256-entry window.
// base = floor(min)-2, clamped to [0, 768] (so base+255 <= 1023).
// ---------------------------------------------------------------------------
__global__ __launch_bounds__(256) void fan_umin_kernel(
    const float2* __restrict__ cs, unsigned* __restrict__ utab) {
    const int t = blockIdx.x * 256 + threadIdx.x;  // 256 tiles * 1024 angles
    const int a = t & (N_A - 1);
    const int tile = t >> 10;
    const float2 p = cs[a];
    const float c = p.x, s = p.y;
    const float x0 = (float)((tile & 15) * 32) - 255.5f;
    const float x1 = x0 + 31.0f;
    const float y0 = (float)((tile >> 4) * 32) - 255.5f;
    const float y1 = y0 + 31.0f;
    float m = 1e30f;
#pragma unroll
    for (int i = 0; i < 4; ++i) {
        const float xx = (i & 1) ? x1 : x0;
        const float yy = (i & 2) ? y1 : y0;
        const float tt = 750.0f + xx * c + yy * s;
        const float idx = (960.0f * (yy * c - xx * s)) / tt + 511.5f;
        m = fminf(m, idx);
    }
    int base = (int)floorf(m) - 2;
    base = base < 0 ? 0 : (base > 768 ? 768 : base);
    utab[t] = (unsigned)base;
}

// ---------------------------------------------------------------------------
// FFT ramp filter: output [g][a][d], 16B entries = 4 batches' bilinear half2
// pair (f[d], f[d+1]).
// ---------------------------------------------------------------------------
__global__ __launch_bounds__(256) void fan_fft_filter4_kernel(
    const float* __restrict__ sino, const float* __restrict__ filt,
    const float* __restrict__ twr_g, const float* __restrict__ twi_g,
    uint4* __restrict__ pf4) {
    __shared__ float s_re0[1024], s_im0[1024];
    __shared__ float s_re1[1024], s_im1[1024];
    __shared__ float s_twr[512], s_twi[512];

    const int tid = threadIdx.x;
    const int a = blockIdx.x & (N_A - 1);
    const int g = blockIdx.x >> 10;

    {
        float2 t0 = ((const float2*)twr_g)[tid];
        s_twr[2 * tid] = t0.x; s_twr[2 * tid + 1] = t0.y;
        float2 t1 = ((const float2*)twi_g)[tid];
        s_twi[2 * tid] = t1.x; s_twi[2 * tid + 1] = t1.y;
    }
    {
        const size_t rowstride = (size_t)N_A * N_D;
        const float* rb = sino + (size_t)(4 * g) * rowstride + (size_t)a * N_D;
        ((float4*)s_re0)[tid] = ((const float4*)(rb + 0 * rowstride))[tid];
        ((float4*)s_im0)[tid] = ((const float4*)(rb + 1 * rowstride))[tid];
        ((float4*)s_re1)[tid] = ((const float4*)(rb + 2 * rowstride))[tid];
        ((float4*)s_im1)[tid] = ((const float4*)(rb + 3 * rowstride))[tid];
    }
    __syncthreads();

    for (int L = 9; L >= 0; --L) {
        const int half = 1 << L;
#pragma unroll
        for (int q = 0; q < 4; ++q) {
            float* re = (q < 2) ? s_re0 : s_re1;
            float* im = (q < 2) ? s_im0 : s_im1;
            const int bf = tid + ((q & 1) << 8);
            const int j = bf & (half - 1);
            const int blk = bf >> L;
            const int base = (blk << (L + 1)) + j;
            const int tw = j << (9 - L);
            const float wr = s_twr[tw], wi = s_twi[tw];
            const float ar = re[base], ai = im[base];
            const float br = re[base + half], bi = im[base + half];
            re[base] = ar + br;
            im[base] = ai + bi;
            const float dr = ar - br, di = ai - bi;
            re[base + half] = dr * wr - di * wi;
            im[base + half] = dr * wi + di * wr;
        }
        __syncthreads();
    }

#pragma unroll
    for (int q = 0; q < 4; ++q) {
        const int i = tid + (q << 8);
        const int ri = (int)(__brev((unsigned)i) >> 22);
        const float f = filt[ri];
        s_re0[i] *= f; s_im0[i] *= f;
        s_re1[i] *= f; s_im1[i] *= f;
    }
    __syncthreads();

    for (int L = 0; L <= 9; ++L) {
        const int half = 1 << L;
#pragma unroll
        for (int q = 0; q < 4; ++q) {
            float* re = (q < 2) ? s_re0 : s_re1;
            float* im = (q < 2) ? s_im0 : s_im1;
            const int bf = tid + ((q & 1) << 8);
            const int j = bf & (half - 1);
            const int blk = bf >> L;
            const int base = (blk << (L + 1)) + j;
            const int tw = j << (9 - L);
            const float wr = s_twr[tw], wi = -s_twi[tw];
            const float ar = re[base], ai = im[base];
            const float tr = re[base + half], ti = im[base + half];
            const float br = tr * wr - ti * wi;
            const float bi = tr * wi + ti * wr;
            re[base] = ar + br;
            im[base] = ai + bi;
            re[base + half] = ar - br;
            im[base + half] = ai - bi;
        }
        __syncthreads();
    }

    const float invN = 1.0f / 1024.0f;
    uint4* dst = pf4 + ((size_t)g * N_A + (size_t)a) * N_D;
#pragma unroll
    for (int q = 0; q < 4; ++q) {
        const int n = tid + (q << 8);
        const int n1 = (n < 1023) ? n + 1 : n;
        const float e = (n < 1023) ? 1.0f : 0.0f;
        uint4 v;
        v.x = pack_u(s_re0[n] * invN, s_re0[n1] * invN * e);
        v.y = pack_u(s_im0[n] * invN, s_im0[n1] * invN * e);
        v.z = pack_u(s_re1[n] * invN, s_re1[n1] * invN * e);
        v.w = pack_u(s_im1[n] * invN, s_im1[n1] * invN * e);
        dst[n] = v;
    }
}

// ---------------------------------------------------------------------------
// Backprojection, hybrid pipes, 2 px/thread, REAL register budget:
// __launch_bounds__(512, 4) grants <=128 VGPR so the 32 accumulators live in
// VGPRs (r15 failed here: default budget -> AGPR shuffling). Angle loop
// unrolled x2 (static window buffer per body); oi wrap (&255) instead of
// clamp (w=0 lanes read in-bounds garbage * 0 -> benign).
// ---------------------------------------------------------------------------
#define ABODY(WB, K_, PF_)                                                    \
    {                                                                         \
        const int k_ = (K_);                                                  \
        (WB)[tid] = pre;                                                      \
        if (PF_) {                                                            \
            const unsigned e_ = s_ub[k_ + 1] + se;                            \
            pre = gsrc[(((unsigned)(abase + k_ + 1)) << 10) + e_];            \
        }                                                                     \
        __syncthreads();                                                      \
        const float2 csp = lcs[k_];                                           \
        const float c = csp.x, s = csp.y;                                     \
        const unsigned ub = s_ub[k_];                                         \
        const unsigned abk = ((unsigned)(abase + k_)) << 10;                  \
        const float t0v = fmaf(x, c, fmaf(y0, s, 750.0f));                    \
        const float num0 = fmaf(y0, c, -(x * s));                             \
        const float t1v = fmaf(16.0f, s, t0v);                                \
        const float num1 = fmaf(16.0f, c, num0);                              \
        const float r0 = __builtin_amdgcn_rcpf(t0v);                          \
        const float r1 = __builtin_amdgcn_rcpf(t1v);                          \
        const float idxA = fmaf(num0 * r0, 960.0f, 511.5f);                   \
        const float idxB = fmaf(num1 * r1, 960.0f, 511.5f);                   \
        const float idxcA = med3f(idxA, 0.0f, 1023.0f);                       \
        const float idxcB = med3f(idxB, 0.0f, 1023.0f);                       \
        const float i0fA = floorf(idxcA);                                     \
        const float i0fB = floorf(idxcB);                                     \
        const float frA = idxcA - i0fA;                                       \
        const float frB = idxcB - i0fB;                                       \
        const float waA = 750.0f * r0, waB = 750.0f * r1;                     \
        float wdA = waA * waA, wdB = waB * waB;                               \
        wdA = (idxA == idxcA) ? wdA : 0.0f;                                   \
        wdB = (idxB == idxcB) ? wdB : 0.0f;                                   \
        const float w1A = wdA * frA, w1B = wdB * frB;                         \
        const half2t wpA = pack_h2(wdA - w1A, w1A);                           \
        const half2t wpB = pack_h2(wdB - w1B, w1B);                           \
        const int i0A = (int)i0fA, i0B = (int)i0fB;                           \
        const unsigned offA = abk + (unsigned)i0A;                            \
        const unsigned offB = abk + (unsigned)i0B;                            \
        const unsigned oiA = ((unsigned)(i0A - (int)ub)) & 255u;              \
        const unsigned oiB = ((unsigned)(i0B - (int)ub)) & 255u;              \
        const uint4 a0 = g0[offA];                                            \
        const uint4 a1 = g1[offA];                                            \
        const uint4 a2 = (WB)[oiA];                                           \
        const uint4 a3 = (WB)[256u + oiA];                                    \
        const uint4 b0 = g0[offB];                                            \
        const uint4 b1 = g1[offB];                                            \
        const uint4 b2 = (WB)[oiB];                                           \
        const uint4 b3 = (WB)[256u + oiB];                                    \
        acc0[0] = fdot2f(h2cast(a0.x), wpA, acc0[0]);                         \
        acc0[1] = fdot2f(h2cast(a0.y), wpA, acc0[1]);                         \
        acc0[2] = fdot2f(h2cast(a0.z), wpA, acc0[2]);                         \
        acc0[3] = fdot2f(h2cast(a0.w), wpA, acc0[3]);                         \
        acc0[4] = fdot2f(h2cast(a1.x), wpA, acc0[4]);                         \
        acc0[5] = fdot2f(h2cast(a1.y), wpA, acc0[5]);                         \
        acc0[6] = fdot2f(h2cast(a1.z), wpA, acc0[6]);                         \
        acc0[7] = fdot2f(h2cast(a1.w), wpA, acc0[7]);                         \
        acc0[8] = fdot2f(h2cast(a2.x), wpA, acc0[8]);                         \
        acc0[9] = fdot2f(h2cast(a2.y), wpA, acc0[9]);                         \
        acc0[10] = fdot2f(h2cast(a2.z), wpA, acc0[10]);                       \
        acc0[11] = fdot2f(h2cast(a2.w), wpA, acc0[11]);                       \
        acc0[12] = fdot2f(h2cast(a3.x), wpA, acc0[12]);                       \
        acc0[13] = fdot2f(h2cast(a3.y), wpA, acc0[13]);                       \
        acc0[14] = fdot2f(h2cast(a3.z), wpA, acc0[14]);                       \
        acc0[15] = fdot2f(h2cast(a3.w), wpA, acc0[15]);                       \
        acc1[0] = fdot2f(h2cast(b0.x), wpB, acc1[0]);                         \
        acc1[1] = fdot2f(h2cast(b0.y), wpB, acc1[1]);                         \
        acc1[2] = fdot2f(h2cast(b0.z), wpB, acc1[2]);                         \
        acc1[3] = fdot2f(h2cast(b0.w), wpB, acc1[3]);                         \
        acc1[4] = fdot2f(h2cast(b1.x), wpB, acc1[4]);                         \
        acc1[5] = fdot2f(h2cast(b1.y), wpB, acc1[5]);                         \
        acc1[6] = fdot2f(h2cast(b1.z), wpB, acc1[6]);                         \
        acc1[7] = fdot2f(h2cast(b1.w), wpB, acc1[7]);                         \
        acc1[8] = fdot2f(h2cast(b2.x), wpB, acc1[8]);                         \
        acc1[9] = fdot2f(h2cast(b2.y), wpB, acc1[9]);                         \
        acc1[10] = fdot2f(h2cast(b2.z), wpB, acc1[10]);                       \
        acc1[11] = fdot2f(h2cast(b2.w), wpB, acc1[11]);                       \
        acc1[12] = fdot2f(h2cast(b3.x), wpB, acc1[12]);                       \
        acc1[13] = fdot2f(h2cast(b3.y), wpB, acc1[13]);                       \
        acc1[14] = fdot2f(h2cast(b3.z), wpB, acc1[14]);                       \
        acc1[15] = fdot2f(h2cast(b3.w), wpB, acc1[15]);                       \
    }

template <int SPLIT>
__global__ __launch_bounds__(512, 4) void fan_backproject_kernel(
    const uint4* __restrict__ pf4, const float2* __restrict__ cs_g,
    const unsigned* __restrict__ utab, float* __restrict__ dst0) {
    constexpr int ACNT = N_A / SPLIT;
    __shared__ float2 lcs[ACNT];
    __shared__ unsigned s_ub[ACNT];
    __shared__ uint4 win[2][512];  // 16 KB: [buf][g*256 + e]
    const int tid = threadIdx.x;   // 0..511

    int part, tile;
    if (SPLIT == 4) {
        part = blockIdx.x & 3;   // round-robin: XCD-local angle slice
        tile = blockIdx.x >> 2;
    } else {
        part = 0;
        tile = blockIdx.x;
    }
    const int abase = part * ACNT;

    // stage loop tables
    const unsigned* __restrict__ utrow = utab + (size_t)tile * N_A + abase;
    for (int i = tid; i < ACNT; i += 512) {
        lcs[i] = cs_g[abase + i];
        s_ub[i] = utrow[i];
    }

    const int xi = (tile & 15) * 32 + (tid & 31);
    const int yi0 = (tile >> 4) * 32 + (tid >> 5);  // rows 0..15 of tile
    const float x = (float)xi - 255.5f;
    const float y0 = (float)yi0 - 255.5f;

    const uint4* __restrict__ g0 = pf4;                       // batches 0-3
    const uint4* __restrict__ g1 = pf4 + ((size_t)1 << 20);   // batches 4-7
    // staging: sg = tid>>8 (0 -> group2, 1 -> group3), se = tid&255
    const unsigned sg = (unsigned)tid >> 8;
    const unsigned se = (unsigned)tid & 255u;
    const uint4* __restrict__ gsrc = pf4 + ((size_t)(2 + sg) << 20);

    float acc0[N_B], acc1[N_B];
#pragma unroll
    for (int b = 0; b < N_B; ++b) { acc0[b] = 0.0f; acc1[b] = 0.0f; }

    uint4* wb0 = &win[0][0];
    uint4* wb1 = &win[1][0];

    __syncthreads();  // tables ready

    // prefetch window(0): s_ub <= 768, se <= 255 -> e <= 1023 in range
    uint4 pre;
    {
        const unsigned e = s_ub[0] + se;
        pre = gsrc[(((unsigned)abase) << 10) + e];
    }

    // unrolled x2: even body -> buf0, odd body -> buf1 (static addressing)
    for (int kk = 0; kk + 2 < ACNT; kk += 2) {
        ABODY(wb0, kk, true);
        ABODY(wb1, kk + 1, true);
    }
    ABODY(wb0, ACNT - 2, true);
    ABODY(wb1, ACNT - 1, false);

    const float scale = 3.14159265358979323846f / 1024.0f;  // pi / A
    float* dst = dst0 + (size_t)part * ((size_t)N_B * N_H * N_W);
    const size_t pix0 = (size_t)yi0 * N_W + (size_t)xi;
    const size_t pix1 = pix0 + (size_t)16 * N_W;
#pragma unroll
    for (int b = 0; b < N_B; ++b) {
        dst[(size_t)b * (N_H * N_W) + pix0] = acc0[b] * scale;
        dst[(size_t)b * (N_H * N_W) + pix1] = acc1[b] * scale;
    }
}

// ---------------------------------------------------------------------------
template <int NS>
__global__ __launch_bounds__(256) void fan_reduce_kernel(
    const float4* __restrict__ p, float4* __restrict__ o) {
    const int i = blockIdx.x * 256 + threadIdx.x;
    const size_t stride = (size_t)N_B * N_H * N_W / 4;
    float4 v = p[i];
#pragma unroll
    for (int k = 1; k < NS; ++k) {
        const float4 w = p[(size_t)k * stride + i];
        v.x += w.x; v.y += w.y; v.z += w.z; v.w += w.w;
    }
    o[i] = v;
}

// ---------------------------------------------------------------------------
extern "C" void kernel_launch(void* const* d_in, const int* in_sizes, int n_in,
                              void* d_out, int out_size, void* d_ws, size_t ws_size,
                              hipStream_t stream) {
    const float* sino = (const float*)d_in[0];    // [16, 1024, 1024] f32
    const float* filt = (const float*)d_in[1];    // [1024] f32
    const float* angles = (const float*)d_in[2];  // [1024] f32
    float* out = (float*)d_out;                   // [16, 512, 512] f32

    float* twr = (float*)d_ws;
    float* twi = twr + 512;
    float2* cs = (float2*)(twi + 512);
    char* base = (char*)d_ws;
    unsigned* utab = (unsigned*)(base + 16384);            // 1 MB
    uint4* pf4 = (uint4*)(base + 16384 + (1 << 20));
    const size_t PF_BYTES = (size_t)4 * N_A * N_D * 16;    // 64 MB
    float* partials = (float*)(base + 16384 + (1 << 20) + PF_BYTES);
    const size_t PART = (size_t)N_B * N_H * N_W;           // 4M floats
    const size_t need4 = 16384 + (1 << 20) + PF_BYTES + 4 * PART * 4;
    const size_t need1 = 16384 + (1 << 20) + PF_BYTES;

    fan_setup_kernel<<<4, 256, 0, stream>>>(angles, twr, twi, cs);
    fan_umin_kernel<<<1024, 256, 0, stream>>>(cs, utab);
    fan_fft_filter4_kernel<<<4 * N_A, 256, 0, stream>>>(sino, filt, twr, twi,
                                                        pf4);
    if (ws_size >= need4) {
        fan_backproject_kernel<4><<<256 * 4, 512, 0, stream>>>(pf4, cs, utab,
                                                               partials);
        fan_reduce_kernel<4><<<(int)(PART / 4 / 256), 256, 0, stream>>>(
            (const float4*)partials, (float4*)out);
    } else if (ws_size >= need1) {
        fan_backproject_kernel<1><<<256, 512, 0, stream>>>(pf4, cs, utab,
                                                           out);
    }
}